// Round 2
// baseline (128.896 us; speedup 1.0000x reference)
//
#include <hip/hip_runtime.h>

#define PI_F 3.14159265358979323846f
#define INV_SQRT2 0.70710678118654752440f

__device__ __forceinline__ float2 cmul(float2 a, float2 b) {
    return make_float2(a.x*b.x - a.y*b.y, a.x*b.y + a.y*b.x);
}

// RY on a register-bit qubit (j-bit BIT). float2 packs re/im -> v_pk_fma_f32.
template<int BIT>
__device__ __forceinline__ void reg_gate(float2* a, float c, float s) {
#pragma unroll
    for (int j = 0; j < 32; ++j) {
        if (!(j & BIT)) {
            const int k = j | BIT;
            const float2 a0 = a[j], a1 = a[k];
            a[j] = make_float2(c*a0.x - s*a1.x, c*a0.y - s*a1.y);
            a[k] = make_float2(s*a0.x + c*a1.x, s*a0.y + c*a1.y);
        }
    }
}

// RY on a lane-bit qubit: cross-lane shuffle (no LDS, no sync).
__device__ __forceinline__ void lane_gate(float2* a, int l, int mask, float c, float s) {
    const float sg = (l & mask) ? s : -s;
#pragma unroll
    for (int j = 0; j < 32; ++j) {
        const float px = __shfl_xor(a[j].x, mask, 64);
        const float py = __shfl_xor(a[j].y, mask, 64);
        a[j] = make_float2(c*a[j].x + sg*px, c*a[j].y + sg*py);
    }
}

// Block decode with XCD swizzle: all 8 blocks of a circuit share blockIdx%8,
// so one circuit's 512 KB state stays in a single XCD's L2.
#define DECODE_BLOCK() \
    const int tid = threadIdx.x; \
    const int xs = blockIdx.x & 7, kk = blockIdx.x >> 3; \
    const int n = (xs << 3) | (kk >> 3); \
    const int g = kk & 7; \
    const int l = tid & 63, wid = tid >> 6;

// ---------------- K1: init product state * phi0, RY(alpha) on state bits 0..10.
// Wave-local amp index: bits0-5 = lane, bits6-10 = j, bits11-15 = w (chunk).
__global__ __launch_bounds__(256, 2)
void k1_init(const float* __restrict__ x, const float* __restrict__ wcrz,
             const float* __restrict__ wry, const float* __restrict__ scale_p,
             float2* __restrict__ st) {
    DECODE_BLOCK();
    const int w = g * 4 + wid;   // chunk bits 11..15

    __shared__ float v0s[16], v1s[16], t0s[16], gc[16], gs[16];
    __shared__ float2 TL[256], TH[256], C0[16];

    if (tid < 16) {
        const int q = tid, b = n >> 3, p = n & 7, h = q >> 2, ww = q & 3;
        const float enc = tanhf(x[b*128 + h*32 + p*4 + ww] * scale_p[0]) * PI_F;
        float sE, cE; sincosf(0.5f * enc, &sE, &cE);
        v0s[q] = (cE - sE) * INV_SQRT2;      // RY(enc)*H |0>
        v1s[q] = (cE + sE) * INV_SQRT2;
        sincosf(0.5f * (wry[q] + enc), &gs[q], &gc[q]);  // merged RY(w0)+RY(enc)
        t0s[q] = 0.5f * wcrz[q];             // layer-0 CRZ half-angles
    }
    __syncthreads();

    {   // TL: state bits 0..7 (product + crz gates q=0..6)
        float prod = 1.f, ang = 0.f;
#pragma unroll
        for (int q = 0; q < 8; ++q) prod *= ((tid >> q) & 1) ? v1s[q] : v0s[q];
#pragma unroll
        for (int i = 0; i < 7; ++i)
            if ((tid >> i) & 1) ang += ((tid >> (i + 1)) & 1) ? t0s[i] : -t0s[i];
        float sa, ca; sincosf(ang, &sa, &ca);
        TL[tid] = make_float2(prod * ca, prod * sa);

        // TH: state bits 8..15 (product + crz gates q=8..14)
        prod = 1.f; ang = 0.f;
#pragma unroll
        for (int q = 0; q < 8; ++q) prod *= ((tid >> q) & 1) ? v1s[q + 8] : v0s[q + 8];
#pragma unroll
        for (int i = 0; i < 7; ++i)
            if ((tid >> i) & 1) ang += ((tid >> (i + 1)) & 1) ? t0s[8 + i] : -t0s[8 + i];
        sincosf(ang, &sa, &ca);
        TH[tid] = make_float2(prod * ca, prod * sa);

        if (tid < 16) {  // cross gates q=7 (b7->b8), q=15 (b15->b0)
            const int b7 = tid & 1, b8 = (tid >> 1) & 1, b15 = (tid >> 2) & 1, b0 = (tid >> 3) & 1;
            float a2 = 0.f;
            if (b7)  a2 += b8 ? t0s[7]  : -t0s[7];
            if (b15) a2 += b0 ? t0s[15] : -t0s[15];
            float s2, c2; sincosf(a2, &s2, &c2);
            C0[tid] = make_float2(c2, s2);
        }
    }
    __syncthreads();

    float2 a[32];
    {
        const int b0 = l & 1, b15 = (w >> 4) & 1;
        float2 G[8];
#pragma unroll
        for (int u = 0; u < 8; ++u) {           // u = j&7 -> state bits 6,7,8
            const int b7 = (u >> 1) & 1, b8 = (u >> 2) & 1;
            G[u] = cmul(TL[l | ((u & 3) << 6)],
                        C0[b7 | (b8 << 1) | (b15 << 2) | (b0 << 3)]);
        }
#pragma unroll
        for (int j = 0; j < 32; ++j)
            a[j] = cmul(G[j & 7], TH[((j >> 2) & 7) | (w << 3)]);
    }

    // RY(alpha) on state bits 6..10 (j bits) and 0..5 (lane bits)
    reg_gate<1 >(a, gc[6],  gs[6]);
    reg_gate<2 >(a, gc[7],  gs[7]);
    reg_gate<4 >(a, gc[8],  gs[8]);
    reg_gate<8 >(a, gc[9],  gs[9]);
    reg_gate<16>(a, gc[10], gs[10]);
#pragma unroll
    for (int q = 0; q < 6; ++q) lane_gate(a, l, 1 << q, gc[q], gs[q]);

    float2* op = st + ((size_t)n << 16) + (w << 11) + l;
#pragma unroll
    for (int j = 0; j < 32; ++j) op[j << 6] = a[j];
}

// ---------------- K2: RY(alpha) bits 11..15, phi1, RY(beta) bits 0..5,11..15.
// Amp index: bits0-5 = lane, bits6-10 = v (chunk), bits11-15 = j.
__global__ __launch_bounds__(256, 2)
void k2_mid(const float* __restrict__ x, const float* __restrict__ wcrz,
            const float* __restrict__ wry, const float* __restrict__ scale_p,
            float2* __restrict__ st) {
    DECODE_BLOCK();
    const int v = g * 4 + wid;   // chunk bits 6..10

    __shared__ float t1s[16], bc[16], bs[16], ac5[5], as5[5];
    __shared__ float2 A1[256], B1[128], D1[128];

    if (tid < 16) {
        const int q = tid, b = n >> 3, p = n & 7, h = q >> 2, ww = q & 3;
        const float enc = tanhf(x[b*128 + h*32 + p*4 + ww] * scale_p[0]) * PI_F;
        if (q >= 11) sincosf(0.5f * (wry[q] + enc), &as5[q - 11], &ac5[q - 11]);
        sincosf(0.5f * wry[16 + q], &bs[q], &bc[q]);
        t1s[q] = 0.5f * wcrz[16 + q];
    }
    __syncthreads();

    {   // A1: idx bits 0..5 = state 0..5, bits 6,7 = state 6,7. gates q=0..5
        float ang = 0.f;
#pragma unroll
        for (int i = 0; i < 6; ++i)
            if ((tid >> i) & 1) ang += ((tid >> (i + 2)) & 1) ? t1s[i] : -t1s[i];
        float s, c; sincosf(ang, &s, &c);
        A1[tid] = make_float2(c, s);

        if (tid < 128) {  // B1: idx bits 0..4 = state 6..10, bits 5,6 = state 11,12. gates q=6..10
            const int t = tid;
            ang = 0.f;
#pragma unroll
            for (int i = 0; i < 5; ++i)
                if ((t >> i) & 1) ang += ((t >> (i + 2)) & 1) ? t1s[6 + i] : -t1s[6 + i];
            sincosf(ang, &s, &c);
            B1[t] = make_float2(c, s);
        } else {          // D1: idx bits 0..4 = state 11..15, bits 5,6 = state 0,1. gates q=11..15
            const int t = tid - 128;
            ang = 0.f;
#pragma unroll
            for (int i = 0; i < 5; ++i)
                if ((t >> i) & 1) ang += ((t >> (i + 2)) & 1) ? t1s[11 + i] : -t1s[11 + i];
            sincosf(ang, &s, &c);
            D1[t] = make_float2(c, s);
        }
    }
    __syncthreads();

    float2 a[32];
    float2* base = st + ((size_t)n << 16) + (v << 6) + l;
#pragma unroll
    for (int j = 0; j < 32; ++j) a[j] = base[j << 11];

    // finish RY(alpha): state bits 11..15 = j bits
    reg_gate<1 >(a, ac5[0], as5[0]);
    reg_gate<2 >(a, ac5[1], as5[1]);
    reg_gate<4 >(a, ac5[2], as5[2]);
    reg_gate<8 >(a, ac5[3], as5[3]);
    reg_gate<16>(a, ac5[4], as5[4]);

    // phi1 pointwise: phase = A1 * B1 * D1
    {
        const float2 pa = A1[l | ((v & 3) << 6)];
        float2 PB[4];
#pragma unroll
        for (int t = 0; t < 4; ++t) PB[t] = cmul(pa, B1[v | (t << 5)]);
        const int dl = (l & 3) << 5;
#pragma unroll
        for (int j = 0; j < 32; ++j)
            a[j] = cmul(a[j], cmul(PB[j & 3], D1[j | dl]));
    }

    // RY(beta) on lane bits 0..5 and j bits 11..15
#pragma unroll
    for (int q = 0; q < 6; ++q) lane_gate(a, l, 1 << q, bc[q], bs[q]);
    reg_gate<1 >(a, bc[11], bs[11]);
    reg_gate<2 >(a, bc[12], bs[12]);
    reg_gate<4 >(a, bc[13], bs[13]);
    reg_gate<8 >(a, bc[14], bs[14]);
    reg_gate<16>(a, bc[15], bs[15]);

#pragma unroll
    for (int j = 0; j < 32; ++j) base[j << 11] = a[j];
}

// ---------------- K3: RY(beta) bits 6..10 + measure -> per-block partial z[16]
__global__ __launch_bounds__(256, 2)
void k3_measure(const float* __restrict__ wry, const float2* __restrict__ st,
                float* __restrict__ partial) {
    DECODE_BLOCK();
    const int w = g * 4 + wid;   // chunk bits 11..15

    float c5[5], s5[5];
#pragma unroll
    for (int i = 0; i < 5; ++i) sincosf(0.5f * wry[16 + 6 + i], &s5[i], &c5[i]);

    float2 a[32];
    const float2* base = st + ((size_t)n << 16) + (w << 11) + l;
#pragma unroll
    for (int j = 0; j < 32; ++j) a[j] = base[j << 6];

    reg_gate<1 >(a, c5[0], s5[0]);
    reg_gate<2 >(a, c5[1], s5[1]);
    reg_gate<4 >(a, c5[2], s5[2]);
    reg_gate<8 >(a, c5[3], s5[3]);
    reg_gate<16>(a, c5[4], s5[4]);

    // vals: P, T0..T4 (j-bit masked sums), M0..M5 (lane-bit masked = P or 0)
    float vals[12];
#pragma unroll
    for (int i = 0; i < 12; ++i) vals[i] = 0.f;
#pragma unroll
    for (int j = 0; j < 32; ++j) {
        const float p = a[j].x*a[j].x + a[j].y*a[j].y;
        vals[0] += p;
#pragma unroll
        for (int i = 0; i < 5; ++i) if ((j >> i) & 1) vals[1 + i] += p;
    }
#pragma unroll
    for (int i = 0; i < 6; ++i) vals[6 + i] = ((l >> i) & 1) ? vals[0] : 0.f;

#pragma unroll
    for (int off = 1; off < 64; off <<= 1)
#pragma unroll
        for (int i = 0; i < 12; ++i) vals[i] += __shfl_xor(vals[i], off, 64);

    __shared__ float wz[4][16];
    if (l == 0) {
        const float P = vals[0];
        float z[16];
#pragma unroll
        for (int i = 0; i < 6; ++i) z[i] = P - 2.f * vals[6 + i];      // lane bits 0..5
#pragma unroll
        for (int i = 0; i < 5; ++i) z[6 + i] = P - 2.f * vals[1 + i];  // j bits 6..10
#pragma unroll
        for (int i = 0; i < 5; ++i) z[11 + i] = ((w >> i) & 1) ? -P : P; // w bits 11..15
#pragma unroll
        for (int q = 0; q < 16; ++q) wz[wid][q] = z[q];
    }
    __syncthreads();
    if (tid < 16)
        partial[(size_t)(n * 8 + g) * 16 + tid] =
            wz[0][tid] + wz[1][tid] + wz[2][tid] + wz[3][tid];
}

// ---------------- K4: reduce 8 block-partials, clip, scatter to output layout
__global__ void k4_out(const float* __restrict__ partial, float* __restrict__ out) {
    const int o = blockIdx.x * 256 + threadIdx.x;   // 1024 outputs
    const int b = o >> 7, r = o & 127;
    const int h = r >> 5, r2 = r & 31, p = r2 >> 2, ww = r2 & 3;
    const int n = b * 8 + p, q = h * 4 + ww;
    float s = 0.f;
#pragma unroll
    for (int g = 0; g < 8; ++g) s += partial[(size_t)(n * 8 + g) * 16 + q];
    out[o] = fminf(1.f, fmaxf(-1.f, s));
}

extern "C" void kernel_launch(void* const* d_in, const int* in_sizes, int n_in,
                              void* d_out, int out_size, void* d_ws, size_t ws_size,
                              hipStream_t stream) {
    const float* x     = (const float*)d_in[0];
    const float* wcrz  = (const float*)d_in[1];
    const float* wry   = (const float*)d_in[2];
    const float* scale = (const float*)d_in[3];
    float2* st      = (float2*)d_ws;
    float* partial  = (float*)((char*)d_ws + (size_t)64 * 65536 * sizeof(float2));
    float* out      = (float*)d_out;

    k1_init   <<<512, 256, 0, stream>>>(x, wcrz, wry, scale, st);
    k2_mid    <<<512, 256, 0, stream>>>(x, wcrz, wry, scale, st);
    k3_measure<<<512, 256, 0, stream>>>(wry, st, partial);
    k4_out    <<<4, 256, 0, stream>>>(partial, out);
}